// Round 5
// baseline (385.618 us; speedup 1.0000x reference)
//
#include <hip/hip_runtime.h>

#define HH 512
#define WW 512
#define NCH 3
#define NBATCH 16
#define NIMG (NBATCH*NCH)     // 48
#define CHUNK 64              // output rows per wave
#define NCHUNK (HH/CHUNK)     // 8
#define NSTRIP 4              // 128-col strips
#define SW 128
#define SLOTS 140             // cols c0-5 .. c0+132 at slot = col-c0+5
#define NT 64                 // one wave per block -> no barriers anywhere
#define NROWS (CHUNK+10)      // 74 input rows per wave

struct RowData { float4 m; float2 h; };
struct Taps { float4 v[6]; };

// R4 lesson: occupancy is LDS-capped at ~2.5 waves/CU (8% measured) and the
// per-row LDS round-trips were fully exposed (VALUBusy 28%). R5: software-
// pipeline one row ahead (issue taps+ring-old for row it+1, then compute row
// it from regs) so ~130 VALU cyc cover the ~190 cyc LDS latency. Same-wave
// LDS is in-order and the compiler preserves same-array LDS op order, so no
// barriers and no asm clobbers are needed. waves_per_eu(1) = min-only: full
// register budget for the pipeline regs (occupancy is LDS-bound anyway).
__global__ __launch_bounds__(NT) __attribute__((amdgpu_waves_per_eu(1)))
void ssim_main(
    const float* __restrict__ pred, const float* __restrict__ targ,
    float* __restrict__ ws)
{
  // row staging: slot s holds (x,y) of col c0+s-5
  __shared__ __align__(16) float2 rowb[SLOTS];
  // vertical ring of horizontal sums: ring0 = col0 (hx,hy,hxy,hss), ring1 = col1
  __shared__ __align__(16) float4 ring0[11][NT];
  __shared__ __align__(16) float4 ring1[11][NT];

  const int l = threadIdx.x;
  const int blk = blockIdx.x;
  const int img = blk >> 5;              // / (NCHUNK*NSTRIP)
  const int rem = blk & 31;
  const int chunk = rem >> 2;
  const int strip = rem & 3;
  const int b = img / NCH;

  const int r0 = chunk*CHUNK - 5;        // first input row
  const int c0 = strip*SW;

  // zero the pad slots once (image-edge strips keep them zero forever)
  if (l < 10) rowb[(l < 5) ? l : (128 + l)] = make_float2(0.f, 0.f);

  const size_t ib = (size_t)img * (size_t)(HH*WW);
  const float* pp = pred + ib;
  const float* tp = targ + ib;

  const int cm = c0 + 2*l;               // this lane's 2 main cols
  const int h  = l - 54;                 // halo id 0..9 on lanes 54..63
  const int ch = (h < 5) ? (c0 - 5 + h) : (c0 + 123 + h);   // halo col
  const bool hval = (l >= 54) && ((unsigned)ch < (unsigned)WW);
  const int hs = (h < 5) ? h : (128 + h);                    // halo slot

  auto loadrow = [&](int it) -> RowData {
    RowData d;
    const int r = r0 + it;
    if ((unsigned)r < (unsigned)HH) {    // wave-uniform branch
      const size_t ro = (size_t)r * WW;
      const float2 x = *(const float2*)(pp + ro + cm);
      const float2 y = *(const float2*)(tp + ro + cm);
      d.m = make_float4(x.x, x.y, y.x, y.y);
      if (hval) d.h = make_float2(pp[ro + ch], tp[ro + ch]);
      else      d.h = make_float2(0.f, 0.f);
    } else {
      d.m = make_float4(0.f, 0.f, 0.f, 0.f);
      d.h = make_float2(0.f, 0.f);
    }
    return d;
  };

  // vertical running sums: (x, y, xy, ss=xx+yy) per col — registers
  float2 vx = make_float2(0.f,0.f), vy = vx, vxy = vx, vss = vx;
  float acc = 0.f;

  // 3-deep global prefetch
  RowData cur = loadrow(0);
  RowData nxt = loadrow(1);
  RowData nx2 = loadrow(2);

  constexpr float c1 = 0.0001f, c2 = 0.0009f, inv121 = 1.0f/121.0f;

  auto ssim1 = [&](float Sx, float Sy, float Sxy, float Sss) -> float {
    const float mux = Sx*inv121, muy = Sy*inv121;
    const float muxy = mux*muy;
    const float m2   = fmaf(mux, mux, muy*muy);
    const float sgxy = fmaf(Sxy, inv121, -muxy);
    const float sgss = fmaf(Sss, inv121, -m2);
    const float num = fmaf(2.f, muxy, c1) * fmaf(2.f, sgxy, c2);
    const float den = (m2 + c1) * (sgss + c2);
    const float s = num * __builtin_amdgcn_rcpf(den);
    return fminf(fmaxf(s, 0.f), 1.f);
  };

  // stage row it into rowb, rotate global prefetch, ISSUE tap reads for it.
  // (in-order LDS pipe: the 6 reads see the 3 writes just issued)
  auto stage_issue = [&](int it) -> Taps {
    rowb[5 + 2*l] = make_float2(cur.m.x, cur.m.z);
    rowb[6 + 2*l] = make_float2(cur.m.y, cur.m.w);
    if (hval) rowb[hs] = cur.h;
    cur = nxt; nxt = nx2;
    nx2 = loadrow(it + 3);
    Taps t;
    const float4* tb = (const float4*)(rowb + 2*l);
    #pragma unroll
    for (int j = 0; j < 6; ++j) t.v[j] = tb[j];
    return t;
  };

  // all-register arithmetic for row it (taps + ring-old already in regs)
  auto compute = [&](const Taps& t, const float4& o0, const float4& o1,
                     int slot, bool dosub, bool doemit) {
    float sx=0.f, sy=0.f, sxy=0.f, sss=0.f;
    float x0=0.f, y0=0.f, x11=0.f, y11=0.f;
    #pragma unroll
    for (int j = 0; j < 6; ++j) {
      const float4 v = t.v[j];           // (x[p], y[p], x[p+1], y[p+1]), p=2j
      if (j == 0) { x0 = v.x; y0 = v.y; }
      sx += v.x; sy += v.y;
      sxy = fmaf(v.x, v.y, sxy);
      sss = fmaf(v.x, v.x, sss);
      sss = fmaf(v.y, v.y, sss);
      if (j < 5) {
        sx += v.z; sy += v.w;
        sxy = fmaf(v.z, v.w, sxy);
        sss = fmaf(v.z, v.z, sss);
        sss = fmaf(v.w, v.w, sss);
      } else { x11 = v.z; y11 = v.w; }
    }
    // col0 window = p0..p10 ; col1 = col0 - p0 + p11
    const float2 hx  = make_float2(sx,  sx - x0 + x11);
    const float2 hy  = make_float2(sy,  sy - y0 + y11);
    const float2 hxy = make_float2(sxy, fmaf(x11, y11, fmaf(-x0, y0, sxy)));
    const float2 hss = make_float2(sss,
        fmaf(x11, x11, fmaf(y11, y11, fmaf(-x0, x0, fmaf(-y0, y0, sss)))));

    if (dosub) {                         // drop row leaving the 11-row window
      vx.x  -= o0.x; vx.y  -= o1.x;
      vy.x  -= o0.y; vy.y  -= o1.y;
      vxy.x -= o0.z; vxy.y -= o1.z;
      vss.x -= o0.w; vss.y -= o1.w;
    }
    ring0[slot][l] = make_float4(hx.x, hy.x, hxy.x, hss.x);
    ring1[slot][l] = make_float4(hx.y, hy.y, hxy.y, hss.y);

    vx.x += hx.x; vx.y += hx.y;  vy.x += hy.x; vy.y += hy.y;
    vxy.x += hxy.x; vxy.y += hxy.y;  vss.x += hss.x; vss.y += hss.y;

    if (doemit) {
      acc += ssim1(vx.x, vy.x, vxy.x, vss.x);
      acc += ssim1(vx.y, vy.y, vxy.y, vss.y);
    }
  };

  // ---- pipelined main loop: 74 bodies, fully unrolled (static slots) ----
  Taps tc = stage_issue(0);
  float4 oc0 = make_float4(0.f,0.f,0.f,0.f), oc1 = oc0;
  #pragma unroll
  for (int it = 0; it < NROWS; ++it) {
    const int slot   = (it < 11) ? it : (it - 11) % 11;
    const bool dosub = (it >= 11);
    const bool doemit= (it >= 10);
    Taps tn;
    float4 no0 = make_float4(0.f,0.f,0.f,0.f), no1 = no0;
    if (it + 1 < NROWS) {
      tn = stage_issue(it + 1);          // issue LDS reads for row it+1 ...
      if (it + 1 >= 11) {                // ... and its ring-old read
        const int ns = (it + 1 - 11) % 11;
        no0 = ring0[ns][l]; no1 = ring1[ns][l];
      }
    }
    compute(tc, oc0, oc1, slot, dosub, doemit);  // VALU covers the reads
    tc = tn; oc0 = no0; oc1 = no1;
  }

  // wave reduction -> one atomic per wave (single-wave block)
  #pragma unroll
  for (int off = 32; off > 0; off >>= 1) acc += __shfl_down(acc, off, 64);
  if (l == 0) atomicAdd(&ws[b], acc);
}

__global__ void ssim_final(const float* __restrict__ ws, float* __restrict__ out) {
  const int i = threadIdx.x;
  if (i < NBATCH) out[i] = 1.0f - ws[i] * (1.0f / (float)(NCH*HH*WW));
}

extern "C" void kernel_launch(void* const* d_in, const int* in_sizes, int n_in,
                              void* d_out, int out_size, void* d_ws, size_t ws_size,
                              hipStream_t stream) {
  const float* pred = (const float*)d_in[0];
  const float* targ = (const float*)d_in[1];
  float* out = (float*)d_out;
  float* ws  = (float*)d_ws;
  hipMemsetAsync(ws, 0, NBATCH * sizeof(float), stream);
  ssim_main<<<dim3(NIMG*NCHUNK*NSTRIP), dim3(NT), 0, stream>>>(pred, targ, ws);
  ssim_final<<<dim3(1), dim3(64), 0, stream>>>(ws, out);
}

// Round 6
// 147.203 us; speedup vs baseline: 2.6196x; 2.6196x over previous
//
#include <hip/hip_runtime.h>
#include <hip/hip_fp16.h>

#define HH 512
#define WW 512
#define NCH 3
#define NBATCH 16
#define NIMG (NBATCH*NCH)     // 48
#define CHUNK 32              // output rows per wave
#define NCHUNK (HH/CHUNK)     // 16
#define NSTRIP 4              // 128-col strips
#define SW 128
#define SLOTS 140             // cols c0-5 .. c0+132 at slot = col-c0+5
#define NT 64                 // one wave per block -> no barriers anywhere
#define NROWS (CHUNK+10)      // 42 input rows per wave
#define BLKS_PER_B (NCH*NCHUNK*NSTRIP)   // 192 partial slots per batch elem

struct RowData { float4 m; float2 h; };

// R4/R5 lessons: register ring spills (R2/R3/R5); LDS fp32 ring works but
// 24 KB caps residency at ~2.5 blocks/CU and the per-row LDS chain is
// exposed (VALUBusy 28%). R6: ring stored in fp16 (h-sums <= 22; the value
// added to V is the SAME rounded value later subtracted -> exact cancel,
// error bounded by in-window quantization ~1e-3 << 1.89e-2 threshold).
// 12.5 KB/block -> 2-5x residency; CHUNK=32 doubles the grid to use it.
__global__ __launch_bounds__(NT) void ssim_main(
    const float* __restrict__ pred, const float* __restrict__ targ,
    float* __restrict__ ws)
{
  // row staging: slot s holds (x,y) of col c0+s-5 (same-wave LDS is in-order;
  // no barriers needed — validated R2-R5, absmax 0.0)
  __shared__ __align__(16) float2 rowb[SLOTS];
  // fp16 ring of horizontal sums: [slot][lane] = {c0:(hx,hy),(hxy,hss), c1:...}
  __shared__ __align__(16) __half2 ring[11][NT][4];

  const int l = threadIdx.x;
  const int blk = blockIdx.x;
  const int img = blk >> 6;              // / (NCHUNK*NSTRIP)
  const int rem = blk & 63;
  const int chunk = rem >> 2;
  const int strip = rem & 3;

  const int r0 = chunk*CHUNK - 5;        // first input row
  const int c0 = strip*SW;

  // zero the pad slots once (image-edge strips keep them zero forever)
  if (l < 10) rowb[(l < 5) ? l : (128 + l)] = make_float2(0.f, 0.f);

  const size_t ib = (size_t)img * (size_t)(HH*WW);
  const float* pp = pred + ib;
  const float* tp = targ + ib;

  const int cm = c0 + 2*l;               // this lane's 2 main cols
  const int h  = l - 54;                 // halo id 0..9 on lanes 54..63
  const int ch = (h < 5) ? (c0 - 5 + h) : (c0 + 123 + h);   // halo col
  const bool hval = (l >= 54) && ((unsigned)ch < (unsigned)WW);
  const int hs = (h < 5) ? h : (128 + h);                    // halo slot

  auto loadrow = [&](int it) -> RowData {
    RowData d;
    const int r = r0 + it;
    if ((unsigned)r < (unsigned)HH) {    // wave-uniform branch
      const size_t ro = (size_t)r * WW;
      const float2 x = *(const float2*)(pp + ro + cm);
      const float2 y = *(const float2*)(tp + ro + cm);
      d.m = make_float4(x.x, x.y, y.x, y.y);
      if (hval) d.h = make_float2(pp[ro + ch], tp[ro + ch]);
      else      d.h = make_float2(0.f, 0.f);
    } else {
      d.m = make_float4(0.f, 0.f, 0.f, 0.f);
      d.h = make_float2(0.f, 0.f);
    }
    return d;
  };

  // vertical running sums: (x, y, xy, ss=xx+yy) per col — registers
  float2 vx = make_float2(0.f,0.f), vy = vx, vxy = vx, vss = vx;
  float acc = 0.f;

  // 3-deep global prefetch
  RowData cur = loadrow(0);
  RowData nxt = loadrow(1);
  RowData nx2 = loadrow(2);

  constexpr float c1 = 0.0001f, c2 = 0.0009f, inv121 = 1.0f/121.0f;

  auto ssim1 = [&](float Sx, float Sy, float Sxy, float Sss) -> float {
    const float mux = Sx*inv121, muy = Sy*inv121;
    const float muxy = mux*muy;
    const float m2   = fmaf(mux, mux, muy*muy);
    const float sgxy = fmaf(Sxy, inv121, -muxy);
    const float sgss = fmaf(Sss, inv121, -m2);
    const float num = fmaf(2.f, muxy, c1) * fmaf(2.f, sgxy, c2);
    const float den = (m2 + c1) * (sgss + c2);
    const float s = num * __builtin_amdgcn_rcpf(den);
    return fminf(fmaxf(s, 0.f), 1.f);
  };

  auto body = [&](int it, int slot, bool dosub, bool doemit) {
    // stage row it (interleaved (x,y) so taps read as aligned float4)
    rowb[5 + 2*l] = make_float2(cur.m.x, cur.m.z);
    rowb[6 + 2*l] = make_float2(cur.m.y, cur.m.w);
    if (hval) rowb[hs] = cur.h;
    cur = nxt; nxt = nx2;
    nx2 = loadrow(it + 3);               // global prefetch 3 rows ahead

    // taps p=0..11 <-> local cols 2l-5 .. 2l+6 <-> slots 2l .. 2l+11
    const float4* tb = (const float4*)(rowb + 2*l);
    float4 tv[6];
    #pragma unroll
    for (int j = 0; j < 6; ++j) tv[j] = tb[j];

    // ring-old read hoisted: constant offsets distinct from this row's
    // writes, so it pipelines with the tap reads
    float2 oxy0, ops0, oxy1, ops1;
    if (dosub) {
      oxy0 = __half22float2(ring[slot][l][0]);
      ops0 = __half22float2(ring[slot][l][1]);
      oxy1 = __half22float2(ring[slot][l][2]);
      ops1 = __half22float2(ring[slot][l][3]);
    }

    float sx=0.f, sy=0.f, sxy=0.f, sss=0.f;
    float x0=0.f, y0=0.f, x11=0.f, y11=0.f;
    #pragma unroll
    for (int j = 0; j < 6; ++j) {
      const float4 v = tv[j];            // (x[p], y[p], x[p+1], y[p+1]), p=2j
      if (j == 0) { x0 = v.x; y0 = v.y; }
      sx += v.x; sy += v.y;
      sxy = fmaf(v.x, v.y, sxy);
      sss = fmaf(v.x, v.x, sss);
      sss = fmaf(v.y, v.y, sss);
      if (j < 5) {
        sx += v.z; sy += v.w;
        sxy = fmaf(v.z, v.w, sxy);
        sss = fmaf(v.z, v.z, sss);
        sss = fmaf(v.w, v.w, sss);
      } else { x11 = v.z; y11 = v.w; }
    }

    // col0 window = p0..p10 ; col1 = col0 - p0 + p11
    const float2 hx  = make_float2(sx,  sx - x0 + x11);
    const float2 hy  = make_float2(sy,  sy - y0 + y11);
    const float2 hxy = make_float2(sxy, fmaf(x11, y11, fmaf(-x0, y0, sxy)));
    const float2 hss = make_float2(sss,
        fmaf(x11, x11, fmaf(y11, y11, fmaf(-x0, x0, fmaf(-y0, y0, sss)))));

    // round h to fp16 once; add the rounded value and store the identical
    // rounded value -> later subtract cancels exactly (no drift)
    const __half2 q0 = __floats2half2_rn(hx.x,  hy.x);
    const __half2 q1 = __floats2half2_rn(hxy.x, hss.x);
    const __half2 q2 = __floats2half2_rn(hx.y,  hy.y);
    const __half2 q3 = __floats2half2_rn(hxy.y, hss.y);
    ring[slot][l][0] = q0; ring[slot][l][1] = q1;
    ring[slot][l][2] = q2; ring[slot][l][3] = q3;
    const float2 a0 = __half22float2(q0), a1 = __half22float2(q1);
    const float2 a2 = __half22float2(q2), a3 = __half22float2(q3);

    if (dosub) {
      vx.x  -= oxy0.x; vy.x  -= oxy0.y; vxy.x -= ops0.x; vss.x -= ops0.y;
      vx.y  -= oxy1.x; vy.y  -= oxy1.y; vxy.y -= ops1.x; vss.y -= ops1.y;
    }
    vx.x += a0.x; vy.x += a0.y; vxy.x += a1.x; vss.x += a1.y;
    vx.y += a2.x; vy.y += a2.y; vxy.y += a3.x; vss.y += a3.y;

    if (doemit) {
      acc += ssim1(vx.x, vy.x, vxy.x, vss.x);
      acc += ssim1(vx.y, vy.y, vxy.y, vss.y);
    }
  };

  // 42 input rows: warmup 11 (first emit at it=10), steady 2x11, tail 9
  #pragma unroll
  for (int u = 0; u < 11; ++u) body(u, u, false, u == 10);
  for (int g = 0; g < 2; ++g) {
    #pragma unroll
    for (int u = 0; u < 11; ++u) body(11 + 11*g + u, u, true, true);
  }
  #pragma unroll
  for (int u = 0; u < 9; ++u) body(33 + u, u, true, true);

  // wave reduction -> per-block partial slot (written unconditionally: no
  // memset of d_ws needed, no atomics)
  #pragma unroll
  for (int off = 32; off > 0; off >>= 1) acc += __shfl_down(acc, off, 64);
  if (l == 0) ws[blk] = acc;
}

__global__ void ssim_final(const float* __restrict__ ws, float* __restrict__ out) {
  const int b = blockIdx.x;              // batch element
  const int t = threadIdx.x;             // 64 threads
  const float* p = ws + b * BLKS_PER_B;
  float s = p[t] + p[t + 64] + p[t + 128];
  #pragma unroll
  for (int off = 32; off > 0; off >>= 1) s += __shfl_down(s, off, 64);
  if (t == 0) out[b] = 1.0f - s * (1.0f / (float)(NCH*HH*WW));
}

extern "C" void kernel_launch(void* const* d_in, const int* in_sizes, int n_in,
                              void* d_out, int out_size, void* d_ws, size_t ws_size,
                              hipStream_t stream) {
  const float* pred = (const float*)d_in[0];
  const float* targ = (const float*)d_in[1];
  float* out = (float*)d_out;
  float* ws  = (float*)d_ws;
  ssim_main<<<dim3(NIMG*NCHUNK*NSTRIP), dim3(NT), 0, stream>>>(pred, targ, ws);
  ssim_final<<<dim3(NBATCH), dim3(64), 0, stream>>>(ws, out);
}

// Round 7
// 146.681 us; speedup vs baseline: 2.6290x; 1.0036x over previous
//
#include <hip/hip_runtime.h>
#include <hip/hip_fp16.h>

#define HH 512
#define WW 512
#define NCH 3
#define NBATCH 16
#define NIMG (NBATCH*NCH)     // 48
#define CHUNK 32              // output rows per wave
#define NCHUNK (HH/CHUNK)     // 16
#define NSTRIP 4              // 128-col strips
#define SW 128
#define SLOTS 140             // cols c0-5 .. c0+132 at slot = col-c0+5
#define NT 64                 // one wave per block -> no barriers anywhere
#define NROWS (CHUNK+10)      // 42 input rows per wave
#define BLKS_PER_B (NCH*NCHUNK*NSTRIP)   // 192 partial slots per batch elem

struct RowData { float4 m; float2 h; };
union RingQ { float4 f; __half2 h[4]; };

// R6 lesson: fp16 ring accessed as 4x half2 (4B ops, 16B lane stride = bank
// stride 4) caused 8-way conflicts (+4.2M cycles). R7: single b128 access
// (float4 bit-cast) — the exact pattern R4 proved conflict-free at 16B/lane.
__global__ __launch_bounds__(NT) void ssim_main(
    const float* __restrict__ pred, const float* __restrict__ targ,
    float* __restrict__ ws)
{
  // row staging: slot s holds (x,y) of col c0+s-5 (same-wave LDS is in-order;
  // no barriers needed — validated R2-R6, absmax 0.0)
  __shared__ __align__(16) float2 rowb[SLOTS];
  // fp16 ring of horizontal sums: one 16B word per (slot,lane):
  // {c0:(hx,hy),(hxy,hss), c1:(hx,hy),(hxy,hss)} — read/write as b128
  __shared__ __align__(16) float4 ring[11][NT];

  const int l = threadIdx.x;
  const int blk = blockIdx.x;
  const int img = blk >> 6;              // / (NCHUNK*NSTRIP)
  const int rem = blk & 63;
  const int chunk = rem >> 2;
  const int strip = rem & 3;

  const int r0 = chunk*CHUNK - 5;        // first input row
  const int c0 = strip*SW;

  // zero the pad slots once (image-edge strips keep them zero forever)
  if (l < 10) rowb[(l < 5) ? l : (128 + l)] = make_float2(0.f, 0.f);

  const size_t ib = (size_t)img * (size_t)(HH*WW);
  const float* pp = pred + ib;
  const float* tp = targ + ib;

  const int cm = c0 + 2*l;               // this lane's 2 main cols
  const int h  = l - 54;                 // halo id 0..9 on lanes 54..63
  const int ch = (h < 5) ? (c0 - 5 + h) : (c0 + 123 + h);   // halo col
  const bool hval = (l >= 54) && ((unsigned)ch < (unsigned)WW);
  const int hs = (h < 5) ? h : (128 + h);                    // halo slot

  auto loadrow = [&](int it) -> RowData {
    RowData d;
    const int r = r0 + it;
    if ((unsigned)r < (unsigned)HH) {    // wave-uniform branch
      const size_t ro = (size_t)r * WW;
      const float2 x = *(const float2*)(pp + ro + cm);
      const float2 y = *(const float2*)(tp + ro + cm);
      d.m = make_float4(x.x, x.y, y.x, y.y);
      if (hval) d.h = make_float2(pp[ro + ch], tp[ro + ch]);
      else      d.h = make_float2(0.f, 0.f);
    } else {
      d.m = make_float4(0.f, 0.f, 0.f, 0.f);
      d.h = make_float2(0.f, 0.f);
    }
    return d;
  };

  // vertical running sums: (x, y, xy, ss=xx+yy) per col — registers
  float2 vx = make_float2(0.f,0.f), vy = vx, vxy = vx, vss = vx;
  float acc = 0.f;

  // 3-deep global prefetch
  RowData cur = loadrow(0);
  RowData nxt = loadrow(1);
  RowData nx2 = loadrow(2);

  constexpr float c1 = 0.0001f, c2 = 0.0009f, inv121 = 1.0f/121.0f;

  auto ssim1 = [&](float Sx, float Sy, float Sxy, float Sss) -> float {
    const float mux = Sx*inv121, muy = Sy*inv121;
    const float muxy = mux*muy;
    const float m2   = fmaf(mux, mux, muy*muy);
    const float sgxy = fmaf(Sxy, inv121, -muxy);
    const float sgss = fmaf(Sss, inv121, -m2);
    const float num = fmaf(2.f, muxy, c1) * fmaf(2.f, sgxy, c2);
    const float den = (m2 + c1) * (sgss + c2);
    const float s = num * __builtin_amdgcn_rcpf(den);
    return fminf(fmaxf(s, 0.f), 1.f);
  };

  auto body = [&](int it, int slot, bool dosub, bool doemit) {
    // stage row it (interleaved (x,y) so taps read as aligned float4)
    rowb[5 + 2*l] = make_float2(cur.m.x, cur.m.z);
    rowb[6 + 2*l] = make_float2(cur.m.y, cur.m.w);
    if (hval) rowb[hs] = cur.h;
    cur = nxt; nxt = nx2;
    nx2 = loadrow(it + 3);               // global prefetch 3 rows ahead

    // taps p=0..11 <-> local cols 2l-5 .. 2l+6 <-> slots 2l .. 2l+11
    const float4* tb = (const float4*)(rowb + 2*l);
    float4 tv[6];
    #pragma unroll
    for (int j = 0; j < 6; ++j) tv[j] = tb[j];

    // ring-old read as ONE b128 (conflict-free 16B/lane pattern)
    RingQ ou;
    if (dosub) ou.f = ring[slot][l];

    float sx=0.f, sy=0.f, sxy=0.f, sss=0.f;
    float x0=0.f, y0=0.f, x11=0.f, y11=0.f;
    #pragma unroll
    for (int j = 0; j < 6; ++j) {
      const float4 v = tv[j];            // (x[p], y[p], x[p+1], y[p+1]), p=2j
      if (j == 0) { x0 = v.x; y0 = v.y; }
      sx += v.x; sy += v.y;
      sxy = fmaf(v.x, v.y, sxy);
      sss = fmaf(v.x, v.x, sss);
      sss = fmaf(v.y, v.y, sss);
      if (j < 5) {
        sx += v.z; sy += v.w;
        sxy = fmaf(v.z, v.w, sxy);
        sss = fmaf(v.z, v.z, sss);
        sss = fmaf(v.w, v.w, sss);
      } else { x11 = v.z; y11 = v.w; }
    }

    // col0 window = p0..p10 ; col1 = col0 - p0 + p11
    const float2 hx  = make_float2(sx,  sx - x0 + x11);
    const float2 hy  = make_float2(sy,  sy - y0 + y11);
    const float2 hxy = make_float2(sxy, fmaf(x11, y11, fmaf(-x0, y0, sxy)));
    const float2 hss = make_float2(sss,
        fmaf(x11, x11, fmaf(y11, y11, fmaf(-x0, x0, fmaf(-y0, y0, sss)))));

    // round h to fp16 once; add the rounded value and store the identical
    // rounded value -> later subtract cancels exactly (no drift)
    RingQ qu;
    qu.h[0] = __floats2half2_rn(hx.x,  hy.x);
    qu.h[1] = __floats2half2_rn(hxy.x, hss.x);
    qu.h[2] = __floats2half2_rn(hx.y,  hy.y);
    qu.h[3] = __floats2half2_rn(hxy.y, hss.y);
    ring[slot][l] = qu.f;                // ONE b128 write
    const float2 a0 = __half22float2(qu.h[0]), a1 = __half22float2(qu.h[1]);
    const float2 a2 = __half22float2(qu.h[2]), a3 = __half22float2(qu.h[3]);

    if (dosub) {
      const float2 oxy0 = __half22float2(ou.h[0]), ops0 = __half22float2(ou.h[1]);
      const float2 oxy1 = __half22float2(ou.h[2]), ops1 = __half22float2(ou.h[3]);
      vx.x  -= oxy0.x; vy.x  -= oxy0.y; vxy.x -= ops0.x; vss.x -= ops0.y;
      vx.y  -= oxy1.x; vy.y  -= oxy1.y; vxy.y -= ops1.x; vss.y -= ops1.y;
    }
    vx.x += a0.x; vy.x += a0.y; vxy.x += a1.x; vss.x += a1.y;
    vx.y += a2.x; vy.y += a2.y; vxy.y += a3.x; vss.y += a3.y;

    if (doemit) {
      acc += ssim1(vx.x, vy.x, vxy.x, vss.x);
      acc += ssim1(vx.y, vy.y, vxy.y, vss.y);
    }
  };

  // 42 input rows: warmup 11 (first emit at it=10), steady 2x11, tail 9
  #pragma unroll
  for (int u = 0; u < 11; ++u) body(u, u, false, u == 10);
  for (int g = 0; g < 2; ++g) {
    #pragma unroll
    for (int u = 0; u < 11; ++u) body(11 + 11*g + u, u, true, true);
  }
  #pragma unroll
  for (int u = 0; u < 9; ++u) body(33 + u, u, true, true);

  // wave reduction -> per-block partial slot (written unconditionally: no
  // memset of d_ws needed, no atomics)
  #pragma unroll
  for (int off = 32; off > 0; off >>= 1) acc += __shfl_down(acc, off, 64);
  if (l == 0) ws[blk] = acc;
}

__global__ void ssim_final(const float* __restrict__ ws, float* __restrict__ out) {
  const int b = blockIdx.x;              // batch element
  const int t = threadIdx.x;             // 64 threads
  const float* p = ws + b * BLKS_PER_B;
  float s = p[t] + p[t + 64] + p[t + 128];
  #pragma unroll
  for (int off = 32; off > 0; off >>= 1) s += __shfl_down(s, off, 64);
  if (t == 0) out[b] = 1.0f - s * (1.0f / (float)(NCH*HH*WW));
}

extern "C" void kernel_launch(void* const* d_in, const int* in_sizes, int n_in,
                              void* d_out, int out_size, void* d_ws, size_t ws_size,
                              hipStream_t stream) {
  const float* pred = (const float*)d_in[0];
  const float* targ = (const float*)d_in[1];
  float* out = (float*)d_out;
  float* ws  = (float*)d_ws;
  ssim_main<<<dim3(NIMG*NCHUNK*NSTRIP), dim3(NT), 0, stream>>>(pred, targ, ws);
  ssim_final<<<dim3(NBATCH), dim3(64), 0, stream>>>(ws, out);
}